// Round 1
// baseline (915.027 us; speedup 1.0000x reference)
//
#include <hip/hip_runtime.h>
#include <math.h>

#define D_MODEL 768
#define NHEADS  12
#define HDIM    64
#define SEQ     1024
#define BATCH   8
#define QKV_COLS (3 * D_MODEL)     // 2304
#define M_TOTAL  (BATCH * SEQ)     // 8192

// 16-FMA microtile update: a components = rows, b components = cols
#define FMA16(a, b, acc)                                                          \
    acc[0][0] += a.x * b.x; acc[0][1] += a.x * b.y; acc[0][2] += a.x * b.z; acc[0][3] += a.x * b.w; \
    acc[1][0] += a.y * b.x; acc[1][1] += a.y * b.y; acc[1][2] += a.y * b.z; acc[1][3] += a.y * b.w; \
    acc[2][0] += a.z * b.x; acc[2][1] += a.z * b.y; acc[2][2] += a.z * b.z; acc[2][3] += a.z * b.w; \
    acc[3][0] += a.w * b.x; acc[3][1] += a.w * b.y; acc[3][2] += a.w * b.z; acc[3][3] += a.w * b.w;

// ---------------------------------------------------------------------------
// Kernel 1: qkv = x @ w_qkv + b_qkv, scattered into q/k/v [B,H,N,hd]
// 64x64 tile, BK=16, 256 threads, 4x4 microtile per thread.
// Column tile (64 wide) == one (which, head) pair exactly.
// ---------------------------------------------------------------------------
__global__ __launch_bounds__(256)
void gemm_qkv_kernel(const float* __restrict__ x, const float* __restrict__ w,
                     const float* __restrict__ bias,
                     float* __restrict__ qout, float* __restrict__ kout,
                     float* __restrict__ vout)
{
    __shared__ float As[16][64];   // [k][m] (transposed A for float4 reads)
    __shared__ float Bs[16][64];   // [k][n]

    const int t  = threadIdx.x;
    const int tx = t & 15, ty = t >> 4;
    const int rowBase = blockIdx.x * 64;
    const int cb      = blockIdx.y;          // 0..35
    const int colBase = cb * 64;

    const int la_r = t >> 2;          // 0..63
    const int la_c = (t & 3) * 4;     // 0,4,8,12
    const int lb_r = t >> 4;          // 0..15
    const int lb_c = (t & 15) * 4;    // 0..60

    float acc[4][4] = {};

    for (int k0 = 0; k0 < D_MODEL; k0 += 16) {
        float4 av = *(const float4*)(x + (size_t)(rowBase + la_r) * D_MODEL + k0 + la_c);
        float4 bv = *(const float4*)(w + (size_t)(k0 + lb_r) * QKV_COLS + colBase + lb_c);
        __syncthreads();   // previous iteration's LDS reads done
        As[la_c + 0][la_r] = av.x;
        As[la_c + 1][la_r] = av.y;
        As[la_c + 2][la_r] = av.z;
        As[la_c + 3][la_r] = av.w;
        *(float4*)&Bs[lb_r][lb_c] = bv;
        __syncthreads();
        #pragma unroll
        for (int kk = 0; kk < 16; ++kk) {
            float4 a = *(const float4*)&As[kk][ty * 4];
            float4 b = *(const float4*)&Bs[kk][tx * 4];
            FMA16(a, b, acc);
        }
    }

    // Epilogue: bias + scatter. which = cb/12, h = cb%12, dd = local col.
    const int which = cb / NHEADS;
    const int h     = cb % NHEADS;
    float* dst = (which == 0) ? qout : (which == 1) ? kout : vout;
    const int b     = rowBase / SEQ;
    const int nBase = rowBase % SEQ;

    #pragma unroll
    for (int i = 0; i < 4; ++i) {
        const int n = nBase + ty * 4 + i;
        float4 r;
        r.x = acc[i][0] + bias[colBase + tx * 4 + 0];
        r.y = acc[i][1] + bias[colBase + tx * 4 + 1];
        r.z = acc[i][2] + bias[colBase + tx * 4 + 2];
        r.w = acc[i][3] + bias[colBase + tx * 4 + 3];
        *(float4*)&dst[(((size_t)b * NHEADS + h) * SEQ + n) * HDIM + tx * 4] = r;
    }
}

// ---------------------------------------------------------------------------
// Kernel 2: flash attention, one block per (b,h, 64-row q tile).
// K/V tiles of 64 in LDS; online softmax; P via LDS for the PV microtile GEMM.
// ---------------------------------------------------------------------------
__global__ __launch_bounds__(256)
void attn_kernel(const float* __restrict__ q, const float* __restrict__ k,
                 const float* __restrict__ v, float* __restrict__ ctx)
{
    __shared__ float Qs[64][64];   // [d][r]
    __shared__ float Ks[64][64];   // [d][c]
    __shared__ float Vs[64][64];   // [j][d]
    __shared__ float Ps[64][64];   // [j][r]

    const int t  = threadIdx.x;
    const int tx = t & 15, ty = t >> 4;
    const int bh = blockIdx.y;               // 0..95
    const int qt = blockIdx.x;               // 0..15
    const size_t base = (size_t)bh * SEQ * HDIM;

    const int lr  = t >> 2;         // 0..63
    const int ld0 = (t & 3) * 16;   // 0,16,32,48

    // Load Q tile transposed [d][r]
    {
        const float* qrow = q + base + (size_t)(qt * 64 + lr) * HDIM;
        #pragma unroll
        for (int u = 0; u < 4; ++u) {
            float4 qv = *(const float4*)(qrow + ld0 + u * 4);
            Qs[ld0 + u * 4 + 0][lr] = qv.x;
            Qs[ld0 + u * 4 + 1][lr] = qv.y;
            Qs[ld0 + u * 4 + 2][lr] = qv.z;
            Qs[ld0 + u * 4 + 3][lr] = qv.w;
        }
    }

    float acc[4][4] = {};
    float m_run[4], l_run[4];
    #pragma unroll
    for (int i = 0; i < 4; ++i) { m_run[i] = -INFINITY; l_run[i] = 0.0f; }

    for (int kt = 0; kt < 16; ++kt) {
        __syncthreads();   // prev PV reads of Ps/Vs done; Qs store visible on kt=0

        const float* krow = k + base + (size_t)(kt * 64 + lr) * HDIM;
        const float* vrow = v + base + (size_t)(kt * 64 + lr) * HDIM;
        #pragma unroll
        for (int u = 0; u < 4; ++u) {
            float4 kv = *(const float4*)(krow + ld0 + u * 4);
            Ks[ld0 + u * 4 + 0][lr] = kv.x;
            Ks[ld0 + u * 4 + 1][lr] = kv.y;
            Ks[ld0 + u * 4 + 2][lr] = kv.z;
            Ks[ld0 + u * 4 + 3][lr] = kv.w;
            *(float4*)&Vs[lr][ld0 + u * 4] = *(const float4*)(vrow + ld0 + u * 4);
        }
        __syncthreads();

        // S tile: s[i][j] = sum_d Q[r][d] * K[c][d]
        float s[4][4] = {};
        #pragma unroll 8
        for (int d = 0; d < 64; ++d) {
            float4 a = *(const float4*)&Qs[d][ty * 4];
            float4 b = *(const float4*)&Ks[d][tx * 4];
            FMA16(a, b, s);
        }

        float p[4][4];
        float alpha[4];
        #pragma unroll
        for (int i = 0; i < 4; ++i) {
            s[i][0] *= 0.125f; s[i][1] *= 0.125f; s[i][2] *= 0.125f; s[i][3] *= 0.125f;
            float mloc = fmaxf(fmaxf(s[i][0], s[i][1]), fmaxf(s[i][2], s[i][3]));
            #pragma unroll
            for (int off = 1; off < 16; off <<= 1)
                mloc = fmaxf(mloc, __shfl_xor(mloc, off));
            const float m_new = fmaxf(m_run[i], mloc);
            alpha[i] = __expf(m_run[i] - m_new);
            m_run[i] = m_new;
            float ls = 0.0f;
            #pragma unroll
            for (int j = 0; j < 4; ++j) {
                p[i][j] = __expf(s[i][j] - m_new);
                ls += p[i][j];
            }
            #pragma unroll
            for (int off = 1; off < 16; off <<= 1)
                ls += __shfl_xor(ls, off);
            l_run[i] = l_run[i] * alpha[i] + ls;
        }

        // P -> LDS (transposed [j][r]) for the PV microtile GEMM
        #pragma unroll
        for (int i = 0; i < 4; ++i)
            #pragma unroll
            for (int j = 0; j < 4; ++j)
                Ps[tx * 4 + j][ty * 4 + i] = p[i][j];
        __syncthreads();

        #pragma unroll
        for (int i = 0; i < 4; ++i) {
            acc[i][0] *= alpha[i]; acc[i][1] *= alpha[i];
            acc[i][2] *= alpha[i]; acc[i][3] *= alpha[i];
        }

        #pragma unroll 8
        for (int jj = 0; jj < 64; ++jj) {
            float4 a = *(const float4*)&Ps[jj][ty * 4];
            float4 b = *(const float4*)&Vs[jj][tx * 4];
            FMA16(a, b, acc);
        }
    }

    // Final: divide by l, write ctx [B, N, D] at column h*64
    const int b = bh / NHEADS, h = bh % NHEADS;
    #pragma unroll
    for (int i = 0; i < 4; ++i) {
        const int n = qt * 64 + ty * 4 + i;
        const float inv = 1.0f / l_run[i];
        float4 r;
        r.x = acc[i][0] * inv; r.y = acc[i][1] * inv;
        r.z = acc[i][2] * inv; r.w = acc[i][3] * inv;
        *(float4*)&ctx[((size_t)b * SEQ + n) * D_MODEL + h * HDIM + tx * 4] = r;
    }
}

// ---------------------------------------------------------------------------
// Kernel 3: out = ctx @ w_proj + b_proj   [8192x768] @ [768x768]
// ---------------------------------------------------------------------------
__global__ __launch_bounds__(256)
void gemm_proj_kernel(const float* __restrict__ a, const float* __restrict__ w,
                      const float* __restrict__ bias, float* __restrict__ out)
{
    __shared__ float As[16][64];
    __shared__ float Bs[16][64];

    const int t  = threadIdx.x;
    const int tx = t & 15, ty = t >> 4;
    const int rowBase = blockIdx.x * 64;
    const int colBase = blockIdx.y * 64;

    const int la_r = t >> 2;
    const int la_c = (t & 3) * 4;
    const int lb_r = t >> 4;
    const int lb_c = (t & 15) * 4;

    float acc[4][4] = {};

    for (int k0 = 0; k0 < D_MODEL; k0 += 16) {
        float4 av = *(const float4*)(a + (size_t)(rowBase + la_r) * D_MODEL + k0 + la_c);
        float4 bv = *(const float4*)(w + (size_t)(k0 + lb_r) * D_MODEL + colBase + lb_c);
        __syncthreads();
        As[la_c + 0][la_r] = av.x;
        As[la_c + 1][la_r] = av.y;
        As[la_c + 2][la_r] = av.z;
        As[la_c + 3][la_r] = av.w;
        *(float4*)&Bs[lb_r][lb_c] = bv;
        __syncthreads();
        #pragma unroll
        for (int kk = 0; kk < 16; ++kk) {
            float4 av2 = *(const float4*)&As[kk][ty * 4];
            float4 bv2 = *(const float4*)&Bs[kk][tx * 4];
            FMA16(av2, bv2, acc);
        }
    }

    #pragma unroll
    for (int i = 0; i < 4; ++i) {
        const int r = rowBase + ty * 4 + i;
        float4 o;
        o.x = acc[i][0] + bias[colBase + tx * 4 + 0];
        o.y = acc[i][1] + bias[colBase + tx * 4 + 1];
        o.z = acc[i][2] + bias[colBase + tx * 4 + 2];
        o.w = acc[i][3] + bias[colBase + tx * 4 + 3];
        *(float4*)&out[(size_t)r * D_MODEL + colBase + tx * 4] = o;
    }
}

// ---------------------------------------------------------------------------
extern "C" void kernel_launch(void* const* d_in, const int* in_sizes, int n_in,
                              void* d_out, int out_size, void* d_ws, size_t ws_size,
                              hipStream_t stream)
{
    const float* x      = (const float*)d_in[0];
    const float* w_qkv  = (const float*)d_in[1];
    const float* b_qkv  = (const float*)d_in[2];
    const float* w_proj = (const float*)d_in[3];
    const float* b_proj = (const float*)d_in[4];
    float* out = (float*)d_out;

    float* ws = (float*)d_ws;
    const size_t qkv_elems = (size_t)BATCH * NHEADS * SEQ * HDIM;   // 6,291,456
    float* q   = ws;
    float* kk  = ws + qkv_elems;
    float* vv  = ws + 2 * qkv_elems;
    float* ctx = ws + 3 * qkv_elems;
    // total ws use: 4 * 6291456 * 4B = 96 MiB

    gemm_qkv_kernel<<<dim3(M_TOTAL / 64, QKV_COLS / 64), 256, 0, stream>>>(
        x, w_qkv, b_qkv, q, kk, vv);
    attn_kernel<<<dim3(SEQ / 64, BATCH * NHEADS), 256, 0, stream>>>(q, kk, vv, ctx);
    gemm_proj_kernel<<<dim3(M_TOTAL / 64, D_MODEL / 64), 256, 0, stream>>>(
        ctx, w_proj, b_proj, out);
}

// Round 2
// 316.251 us; speedup vs baseline: 2.8934x; 2.8934x over previous
//
#include <hip/hip_runtime.h>
#include <math.h>

#define D_MODEL 768
#define NHEADS  12
#define HDIM    64
#define SEQ     1024
#define BATCH   8
#define NBH     (BATCH*NHEADS)          // 96
#define M_TOTAL (BATCH*SEQ)             // 8192
#define KT_D    (D_MODEL/32)            // 24
#define QKV_COLS (3*D_MODEL)            // 2304

typedef __attribute__((ext_vector_type(8))) short bf16x8;
typedef __attribute__((ext_vector_type(4))) float f32x4;

#define MFMA16(a,b,c) __builtin_amdgcn_mfma_f32_16x16x32_bf16((a),(b),(c),0,0,0)

// ---- bf16 split helpers (RNE) ------------------------------------------------
__device__ inline unsigned short f2bf(float f) {
    unsigned u = __float_as_uint(f);
    u += 0x7FFFu + ((u >> 16) & 1u);
    return (unsigned short)(u >> 16);
}
__device__ inline float bf2f(unsigned short h) {
    return __uint_as_float(((unsigned)h) << 16);
}
__device__ inline void split2(float x, unsigned short& hi, unsigned short& lo) {
    hi = f2bf(x);
    lo = f2bf(x - bf2f(hi));
}
__device__ inline void gload16(const void* g, const void* l) {
    __builtin_amdgcn_global_load_lds(
        (const __attribute__((address_space(1))) unsigned*)g,
        (__attribute__((address_space(3))) unsigned*)l, 16, 0, 0);
}
// bijective lane swizzle for the P LDS buffer (spreads 8-way write conflict to 2-way)
__device__ inline int swz(int lp) { return lp ^ ((lp >> 2) & 3) ^ ((lp >> 4) & 3); }

// Fragment container: one 16x32 subtile = [2 planes(hi,lo)][64 lanes][8 elems] ushort
// = 1024 ushorts = 2048 B.  A-frag: lane = (row%16) + ((k%32)/8)*16, slot = k%8.
// B-frag identical with row->col.

// ---- convert x (fp32 row-major [M][K]) -> A-fragments ------------------------
__global__ __launch_bounds__(256)
void convert_a(const float* __restrict__ src, unsigned short* __restrict__ dst,
               int KTn, int ld, float scale, int total)
{
    const int gid = blockIdx.x * 256 + threadIdx.x;
    if (gid >= total) return;
    const int lane = gid & 63;
    const int sub  = gid >> 6;
    const int kt = sub % KTn;
    const int mt = sub / KTn;
    const float* s = src + (size_t)(mt*16 + (lane & 15)) * ld + kt*32 + (lane >> 4)*8;
    float4 v0 = *(const float4*)(s);
    float4 v1 = *(const float4*)(s + 4);
    float vv[8] = {v0.x, v0.y, v0.z, v0.w, v1.x, v1.y, v1.z, v1.w};
    union { unsigned short u[8]; bf16x8 v; } H, L;
    #pragma unroll
    for (int i = 0; i < 8; ++i) split2(vv[i] * scale, H.u[i], L.u[i]);
    unsigned short* d = dst + (size_t)sub * 1024 + lane * 8;
    *(bf16x8*)(d)       = H.v;
    *(bf16x8*)(d + 512) = L.v;
}

// ---- convert weights (fp32 [K][N]) -> B-fragments ----------------------------
__global__ __launch_bounds__(256)
void convert_b(const float* __restrict__ src, unsigned short* __restrict__ dst,
               int KTn, int ldN, int total)
{
    const int gid = blockIdx.x * 256 + threadIdx.x;
    if (gid >= total) return;
    const int lane = gid & 63;
    const int sub  = gid >> 6;
    const int kt = sub % KTn;
    const int nt = sub / KTn;
    const int n  = nt*16 + (lane & 15);
    const int k0 = kt*32 + (lane >> 4)*8;
    const float* s = src + (size_t)k0 * ldN + n;
    union { unsigned short u[8]; bf16x8 v; } H, L;
    #pragma unroll
    for (int i = 0; i < 8; ++i) split2(s[(size_t)i * ldN], H.u[i], L.u[i]);
    unsigned short* d = dst + (size_t)sub * 1024 + lane * 8;
    *(bf16x8*)(d)       = H.v;
    *(bf16x8*)(d + 512) = L.v;
}

// ---- split-bf16 MFMA GEMM, 128x128 tile, BK=32, 4 waves ----------------------
// MODE 0: epilogue scatters (x@w_qkv + b) into Q/K/V fragment buffers
//         (Q pre-scaled by 1/8).  MODE 1: plain fp32 out + bias.
template<int MODE>
__global__ __launch_bounds__(256)
void gemm_frag(const unsigned short* __restrict__ Af,
               const unsigned short* __restrict__ Bf,
               const float* __restrict__ bias,
               float* __restrict__ outF,
               unsigned short* __restrict__ outQ,
               unsigned short* __restrict__ outK,
               unsigned short* __restrict__ outV)
{
    __shared__ unsigned short Asm[8 * 1024];
    __shared__ unsigned short Bsm[8 * 1024];
    const int t = threadIdx.x, lane = t & 63, wid = t >> 6;
    const int wr = wid >> 1, wc = wid & 1;
    const int mb = blockIdx.x, nb = blockIdx.y;

    f32x4 acc[4][4] = {};

    for (int kt = 0; kt < KT_D; ++kt) {
        __syncthreads();                       // prior LDS reads done
        #pragma unroll
        for (int i = 0; i < 4; ++i) {
            const int id = i*256 + t;          // chunk 0..1023
            const unsigned short* ga = Af + ((size_t)(mb*8 + (id >> 7))*KT_D + kt)*1024 + (id & 127)*8;
            gload16(ga, (const char*)Asm + (size_t)(i*256 + wid*64)*16);
            const unsigned short* gb = Bf + ((size_t)(nb*8 + (id >> 7))*KT_D + kt)*1024 + (id & 127)*8;
            gload16(gb, (const char*)Bsm + (size_t)(i*256 + wid*64)*16);
        }
        __syncthreads();                       // staging complete (vmcnt drained)

        bf16x8 ah[4], al[4], bh[4], bl[4];
        #pragma unroll
        for (int m = 0; m < 4; ++m) {
            ah[m] = *(const bf16x8*)(Asm + (wr*4 + m)*1024 + lane*8);
            al[m] = *(const bf16x8*)(Asm + (wr*4 + m)*1024 + 512 + lane*8);
        }
        #pragma unroll
        for (int n = 0; n < 4; ++n) {
            bh[n] = *(const bf16x8*)(Bsm + (wc*4 + n)*1024 + lane*8);
            bl[n] = *(const bf16x8*)(Bsm + (wc*4 + n)*1024 + 512 + lane*8);
        }
        #pragma unroll
        for (int m = 0; m < 4; ++m)
            #pragma unroll
            for (int n = 0; n < 4; ++n) {
                acc[m][n] = MFMA16(ah[m], bh[n], acc[m][n]);
                acc[m][n] = MFMA16(ah[m], bl[n], acc[m][n]);
                acc[m][n] = MFMA16(al[m], bh[n], acc[m][n]);
            }
    }

    const int rowW = mb*128 + wr*64;
    const int colW = nb*128 + wc*64;
    if (MODE == 1) {
        #pragma unroll
        for (int m = 0; m < 4; ++m)
            #pragma unroll
            for (int n = 0; n < 4; ++n) {
                const int col = colW + n*16 + (lane & 15);
                const float bv = bias[col];
                #pragma unroll
                for (int r = 0; r < 4; ++r) {
                    const int row = rowW + m*16 + (lane >> 4)*4 + r;
                    outF[(size_t)row * D_MODEL + col] = acc[m][n][r] + bv;
                }
            }
    } else {
        #pragma unroll
        for (int m = 0; m < 4; ++m)
            #pragma unroll
            for (int n = 0; n < 4; ++n) {
                const int col = colW + n*16 + (lane & 15);
                const int which = col / D_MODEL;
                const int c = col % D_MODEL;
                const int h = c >> 6, d = c & 63;
                const float bv = bias[col];
                unsigned short* dstB = (which == 0) ? outQ : (which == 1) ? outK : outV;
                #pragma unroll
                for (int r = 0; r < 4; ++r) {
                    const int row = rowW + m*16 + (lane >> 4)*4 + r;
                    const int b = row >> 10, sq = row & 1023;
                    float val = acc[m][n][r] + bv;
                    if (which == 0) val *= 0.125f;       // fold softmax scale into Q
                    int sub, lp, slot;
                    if (which == 2) {                    // V: B-frag, outer=d, k=seq
                        sub  = (d >> 4)*32 + (sq >> 5);
                        lp   = (d & 15) + (((sq & 31) >> 3) << 4);
                        slot = sq & 7;
                    } else {                             // Q/K: outer=seq, k=d
                        sub  = (sq >> 4)*2 + (d >> 5);
                        lp   = (sq & 15) + (((d & 31) >> 3) << 4);
                        slot = d & 7;
                    }
                    unsigned short hi, lo; split2(val, hi, lo);
                    unsigned short* p = dstB + (size_t)(b*NHEADS + h)*131072
                                      + (size_t)sub*1024 + lp*8 + slot;
                    p[0]   = hi;
                    p[512] = lo;
                }
            }
    }
}

// ---- flash attention on fragments: 4 waves x 32 q-rows, KV tiles of 64 -------
__global__ __launch_bounds__(256)
void attn_frag(const unsigned short* __restrict__ Qf,
               const unsigned short* __restrict__ Kf,
               const unsigned short* __restrict__ Vf,
               unsigned short* __restrict__ Cf)
{
    __shared__ unsigned short Ksm[8 * 1024];   // 4 nt x 2 kt subtiles
    __shared__ unsigned short Vsm[8 * 1024];   // 4 dt x 2 kt subtiles
    __shared__ unsigned int   Psm[4 * 2048];   // per-wave P: 4 subtiles x 512 words

    const int t = threadIdx.x, lane = t & 63, wid = t >> 6;
    const int bh = blockIdx.y, qb = blockIdx.x;
    const int mt0 = qb*8 + wid*2;              // wave's first q-subtile (of 64)
    const size_t bhBase = (size_t)bh * 131072;

    // Q fragments live in registers for the whole kernel (already scaled by 1/8)
    bf16x8 qh[2][2], ql[2][2];
    #pragma unroll
    for (int m = 0; m < 2; ++m)
        #pragma unroll
        for (int kt = 0; kt < 2; ++kt) {
            const unsigned short* p = Qf + bhBase + ((size_t)(mt0 + m)*2 + kt)*1024 + lane*8;
            qh[m][kt] = *(const bf16x8*)(p);
            ql[m][kt] = *(const bf16x8*)(p + 512);
        }

    f32x4 out[2][4] = {};
    float m_run[2][4], l_run[2][4];
    #pragma unroll
    for (int m = 0; m < 2; ++m)
        #pragma unroll
        for (int r = 0; r < 4; ++r) { m_run[m][r] = -INFINITY; l_run[m][r] = 0.f; }

    unsigned int* Pw = Psm + wid * 2048;

    for (int jt = 0; jt < 16; ++jt) {
        __syncthreads();                       // prev tile's K/V reads done
        #pragma unroll
        for (int i = 0; i < 4; ++i) {
            const int id = i*256 + t;
            const int lsub = id >> 7;
            const unsigned short* gk = Kf + bhBase + (size_t)(jt*8 + lsub)*1024 + (id & 127)*8;
            gload16(gk, (const char*)Ksm + (size_t)(i*256 + wid*64)*16);
            const unsigned short* gv = Vf + bhBase
                + (size_t)((lsub >> 1)*32 + jt*2 + (lsub & 1))*1024 + (id & 127)*8;
            gload16(gv, (const char*)Vsm + (size_t)(i*256 + wid*64)*16);
        }
        __syncthreads();                       // staging complete

        // S = Q K^T (C-layout: lane owns col j = lane&15, rows q = (lane>>4)*4+r)
        f32x4 s[2][4] = {};
        #pragma unroll
        for (int jn = 0; jn < 4; ++jn)
            #pragma unroll
            for (int kt = 0; kt < 2; ++kt) {
                const bf16x8 kh = *(const bf16x8*)(Ksm + (jn*2 + kt)*1024 + lane*8);
                const bf16x8 kl = *(const bf16x8*)(Ksm + (jn*2 + kt)*1024 + 512 + lane*8);
                #pragma unroll
                for (int m = 0; m < 2; ++m) {
                    s[m][jn] = MFMA16(qh[m][kt], kh, s[m][jn]);
                    s[m][jn] = MFMA16(qh[m][kt], kl, s[m][jn]);
                    s[m][jn] = MFMA16(ql[m][kt], kh, s[m][jn]);
                }
            }

        // online softmax + pack P (hi|lo) into per-wave LDS in A-frag order
        float alpha[2][4];
        #pragma unroll
        for (int m = 0; m < 2; ++m)
            #pragma unroll
            for (int r = 0; r < 4; ++r) {
                float mx = fmaxf(fmaxf(s[m][0][r], s[m][1][r]), fmaxf(s[m][2][r], s[m][3][r]));
                #pragma unroll
                for (int msk = 1; msk < 16; msk <<= 1)
                    mx = fmaxf(mx, __shfl_xor(mx, msk));
                const float mn = fmaxf(m_run[m][r], mx);
                const float al_ = __expf(m_run[m][r] - mn);
                m_run[m][r] = mn;
                float rowsum = 0.f;
                unsigned w[4];
                #pragma unroll
                for (int jn = 0; jn < 4; ++jn) {
                    const float e = __expf(s[m][jn][r] - mn);
                    rowsum += e;
                    unsigned short hi, lo; split2(e, hi, lo);
                    w[jn] = (unsigned)hi | ((unsigned)lo << 16);
                }
                #pragma unroll
                for (int msk = 1; msk < 16; msk <<= 1)
                    rowsum += __shfl_xor(rowsum, msk);
                l_run[m][r] = l_run[m][r] * al_ + rowsum;
                alpha[m][r] = al_;
                const int lpb = (lane >> 4)*4 + r;
                #pragma unroll
                for (int jn = 0; jn < 4; ++jn) {
                    const int lpf = lpb + (((jn & 1)*2 + ((lane & 15) >> 3)) << 4);
                    Pw[((m*2) + (jn >> 1))*512 + swz(lpf)*8 + (lane & 7)] = w[jn];
                }
            }

        #pragma unroll
        for (int m = 0; m < 2; ++m)
            #pragma unroll
            for (int dt = 0; dt < 4; ++dt)
                #pragma unroll
                for (int r = 0; r < 4; ++r)
                    out[m][dt][r] *= alpha[m][r];

        // PV: read P back as A-frags (wave-local, no barrier needed), V from LDS
        #pragma unroll
        for (int kt2 = 0; kt2 < 2; ++kt2) {
            bf16x8 pah[2], pal[2];
            #pragma unroll
            for (int m = 0; m < 2; ++m) {
                const unsigned* pp = Pw + (m*2 + kt2)*512 + swz(lane)*8;
                uint4 u0 = *(const uint4*)(pp);
                uint4 u1 = *(const uint4*)(pp + 4);
                union { unsigned w[4]; bf16x8 v; } H, L;
                H.w[0] = (u0.x & 0xFFFFu) | (u0.y << 16);
                H.w[1] = (u0.z & 0xFFFFu) | (u0.w << 16);
                H.w[2] = (u1.x & 0xFFFFu) | (u1.y << 16);
                H.w[3] = (u1.z & 0xFFFFu) | (u1.w << 16);
                L.w[0] = (u0.x >> 16) | (u0.y & 0xFFFF0000u);
                L.w[1] = (u0.z >> 16) | (u0.w & 0xFFFF0000u);
                L.w[2] = (u1.x >> 16) | (u1.w & 0xFFFF0000u ? (u1.w & 0xFFFF0000u) & 0 : 0); // placeholder
                L.w[2] = (u1.x >> 16) | (u1.y & 0xFFFF0000u);
                L.w[3] = (u1.z >> 16) | (u1.w & 0xFFFF0000u);
                pah[m] = H.v; pal[m] = L.v;
            }
            #pragma unroll
            for (int dt = 0; dt < 4; ++dt) {
                const bf16x8 vh = *(const bf16x8*)(Vsm + (dt*2 + kt2)*1024 + lane*8);
                const bf16x8 vl = *(const bf16x8*)(Vsm + (dt*2 + kt2)*1024 + 512 + lane*8);
                #pragma unroll
                for (int m = 0; m < 2; ++m) {
                    out[m][dt] = MFMA16(pah[m], vh, out[m][dt]);
                    out[m][dt] = MFMA16(pah[m], vl, out[m][dt]);
                    out[m][dt] = MFMA16(pal[m], vh, out[m][dt]);
                }
            }
        }
    }

    // epilogue: ctx / l  ->  proj-GEMM A-fragments
    const int b = bh / NHEADS, h = bh % NHEADS;
    #pragma unroll
    for (int m = 0; m < 2; ++m)
        #pragma unroll
        for (int r = 0; r < 4; ++r) {
            const float inv = 1.0f / l_run[m][r];
            const int sq = (mt0 + m)*16 + (lane >> 4)*4 + r;
            const int mrow = b*SEQ + sq;
            #pragma unroll
            for (int dt = 0; dt < 4; ++dt) {
                const int c = h*64 + dt*16 + (lane & 15);
                const float val = out[m][dt][r] * inv;
                unsigned short hi, lo; split2(val, hi, lo);
                unsigned short* p = Cf + ((size_t)(mrow >> 4)*KT_D + (c >> 5))*1024
                                  + ((mrow & 15) + (((c & 31) >> 3) << 4))*8 + (c & 7);
                p[0]   = hi;
                p[512] = lo;
            }
        }
}

// ---------------------------------------------------------------------------
extern "C" void kernel_launch(void* const* d_in, const int* in_sizes, int n_in,
                              void* d_out, int out_size, void* d_ws, size_t ws_size,
                              hipStream_t stream)
{
    const float* x      = (const float*)d_in[0];
    const float* w_qkv  = (const float*)d_in[1];
    const float* b_qkv  = (const float*)d_in[2];
    const float* w_proj = (const float*)d_in[3];
    const float* b_proj = (const float*)d_in[4];
    float* out = (float*)d_out;

    unsigned short* ws = (unsigned short*)d_ws;
    unsigned short* Xf = ws;                    // 512*24*1024        = 12,582,912
    unsigned short* Wq = Xf + 12582912;         // 144*24*1024        =  3,538,944
    unsigned short* Wp = Wq + 3538944;          //  48*24*1024        =  1,179,648
    unsigned short* Qf = Wp + 1179648;          //  96*131072         = 12,582,912
    unsigned short* Kf = Qf + 12582912;
    unsigned short* Vf = Kf + 12582912;
    unsigned short* Cf = Vf + 12582912;         // 512*24*1024
    // total = 67,633,152 ushorts = 135.3 MB of d_ws

    convert_a<<<dim3(3072), 256, 0, stream>>>(x, Xf, KT_D, D_MODEL, 1.0f, 786432);
    convert_b<<<dim3(864),  256, 0, stream>>>(w_qkv, Wq, KT_D, QKV_COLS, 221184);
    convert_b<<<dim3(288),  256, 0, stream>>>(w_proj, Wp, KT_D, D_MODEL, 73728);

    gemm_frag<0><<<dim3(64, 18), 256, 0, stream>>>(Xf, Wq, b_qkv, nullptr, Qf, Kf, Vf);
    attn_frag<<<dim3(8, 96), 256, 0, stream>>>(Qf, Kf, Vf, Cf);
    gemm_frag<1><<<dim3(64, 6), 256, 0, stream>>>(Cf, Wp, b_proj, out,
                                                  nullptr, nullptr, nullptr);
}

// Round 3
// 263.485 us; speedup vs baseline: 3.4728x; 1.2003x over previous
//
#include <hip/hip_runtime.h>
#include <math.h>

#define D_MODEL 768
#define NHEADS  12
#define HDIM    64
#define SEQ     1024
#define BATCH   8
#define NBH     (BATCH*NHEADS)          // 96
#define M_TOTAL (BATCH*SEQ)             // 8192
#define KT_D    (D_MODEL/32)            // 24
#define QKV_COLS (3*D_MODEL)            // 2304

typedef __attribute__((ext_vector_type(8))) short bf16x8;
typedef __attribute__((ext_vector_type(4))) float f32x4;

#define MFMA16(a,b,c) __builtin_amdgcn_mfma_f32_16x16x32_bf16((a),(b),(c),0,0,0)

// Q pre-scale: 1/sqrt(64) * log2(e) so softmax runs in exp2 domain
#define QSCALE 0.18033688011112042f

// ---- bf16 split helpers (RNE) ------------------------------------------------
__device__ inline unsigned short f2bf(float f) {
    unsigned u = __float_as_uint(f);
    u += 0x7FFFu + ((u >> 16) & 1u);
    return (unsigned short)(u >> 16);
}
__device__ inline float bf2f(unsigned short h) {
    return __uint_as_float(((unsigned)h) << 16);
}
__device__ inline void split2(float x, unsigned short& hi, unsigned short& lo) {
    hi = f2bf(x);
    lo = f2bf(x - bf2f(hi));
}
__device__ inline void gload16(const void* g, const void* l) {
    __builtin_amdgcn_global_load_lds(
        (const __attribute__((address_space(1))) unsigned*)g,
        (__attribute__((address_space(3))) unsigned*)l, 16, 0, 0);
}
__device__ inline float exp2_fast(float x) {
#if __has_builtin(__builtin_amdgcn_exp2f)
    return __builtin_amdgcn_exp2f(x);
#else
    float r; asm("v_exp_f32 %0, %1" : "=v"(r) : "v"(x)); return r;
#endif
}

// Fragment container: one 16x32 subtile = [2 planes(hi,lo)][64 lanes][8 elems] ushort
// = 1024 ushorts = 2048 B.  A-frag: lane = (row%16) + ((k%32)/8)*16, slot = k%8.
// B-frag identical with row->col.

// ---- convert x (fp32 row-major [M][K]) -> A-fragments ------------------------
__global__ __launch_bounds__(256)
void convert_a(const float* __restrict__ src, unsigned short* __restrict__ dst,
               int KTn, int ld, float scale, int total)
{
    const int gid = blockIdx.x * 256 + threadIdx.x;
    if (gid >= total) return;
    const int lane = gid & 63;
    const int sub  = gid >> 6;
    const int kt = sub % KTn;
    const int mt = sub / KTn;
    const float* s = src + (size_t)(mt*16 + (lane & 15)) * ld + kt*32 + (lane >> 4)*8;
    float4 v0 = *(const float4*)(s);
    float4 v1 = *(const float4*)(s + 4);
    float vv[8] = {v0.x, v0.y, v0.z, v0.w, v1.x, v1.y, v1.z, v1.w};
    union { unsigned short u[8]; bf16x8 v; } H, L;
    #pragma unroll
    for (int i = 0; i < 8; ++i) split2(vv[i] * scale, H.u[i], L.u[i]);
    unsigned short* d = dst + (size_t)sub * 1024 + lane * 8;
    *(bf16x8*)(d)       = H.v;
    *(bf16x8*)(d + 512) = L.v;
}

// ---- convert weights (fp32 [K][N]) -> B-fragments ----------------------------
__global__ __launch_bounds__(256)
void convert_b(const float* __restrict__ src, unsigned short* __restrict__ dst,
               int KTn, int ldN, int total)
{
    const int gid = blockIdx.x * 256 + threadIdx.x;
    if (gid >= total) return;
    const int lane = gid & 63;
    const int sub  = gid >> 6;
    const int kt = sub % KTn;
    const int nt = sub / KTn;
    const int n  = nt*16 + (lane & 15);
    const int k0 = kt*32 + (lane >> 4)*8;
    const float* s = src + (size_t)k0 * ldN + n;
    union { unsigned short u[8]; bf16x8 v; } H, L;
    #pragma unroll
    for (int i = 0; i < 8; ++i) split2(s[(size_t)i * ldN], H.u[i], L.u[i]);
    unsigned short* d = dst + (size_t)sub * 1024 + lane * 8;
    *(bf16x8*)(d)       = H.v;
    *(bf16x8*)(d + 512) = L.v;
}

// ---- split-bf16 MFMA GEMM, 128x128 tile, BK=32, 4 waves ----------------------
// 1-D grid with XCD-aware swizzle: 8 consecutive mb-panels per XCD -> A-panel
// (3 MB) stays L2-resident while nb sweeps.
// MODE 0: epilogue scatters (x@w_qkv + b) into Q/K/V fragment buffers
//         (Q pre-scaled by QSCALE).  MODE 1: plain fp32 out + bias.
template<int MODE>
__global__ __launch_bounds__(256)
void gemm_frag(const unsigned short* __restrict__ Af,
               const unsigned short* __restrict__ Bf,
               const float* __restrict__ bias,
               float* __restrict__ outF,
               unsigned short* __restrict__ outQ,
               unsigned short* __restrict__ outK,
               unsigned short* __restrict__ outV)
{
    __shared__ unsigned short Asm[8 * 1024];
    __shared__ unsigned short Bsm[8 * 1024];
    const int t = threadIdx.x, lane = t & 63, wid = t >> 6;
    const int wr = wid >> 1, wc = wid & 1;
    const int bid = blockIdx.x;
    const int mb = (bid & 7) * 8 + ((bid >> 3) & 7);
    const int nb = bid >> 6;

    f32x4 acc[4][4] = {};

    for (int kt = 0; kt < KT_D; ++kt) {
        __syncthreads();                       // prior LDS reads done
        #pragma unroll
        for (int i = 0; i < 4; ++i) {
            const int id = i*256 + t;          // chunk 0..1023
            const unsigned short* ga = Af + ((size_t)(mb*8 + (id >> 7))*KT_D + kt)*1024 + (id & 127)*8;
            gload16(ga, (const char*)Asm + (size_t)(i*256 + wid*64)*16);
            const unsigned short* gb = Bf + ((size_t)(nb*8 + (id >> 7))*KT_D + kt)*1024 + (id & 127)*8;
            gload16(gb, (const char*)Bsm + (size_t)(i*256 + wid*64)*16);
        }
        __syncthreads();                       // staging complete (vmcnt drained)

        bf16x8 ah[4], al[4], bh[4], bl[4];
        #pragma unroll
        for (int m = 0; m < 4; ++m) {
            ah[m] = *(const bf16x8*)(Asm + (wr*4 + m)*1024 + lane*8);
            al[m] = *(const bf16x8*)(Asm + (wr*4 + m)*1024 + 512 + lane*8);
        }
        #pragma unroll
        for (int n = 0; n < 4; ++n) {
            bh[n] = *(const bf16x8*)(Bsm + (wc*4 + n)*1024 + lane*8);
            bl[n] = *(const bf16x8*)(Bsm + (wc*4 + n)*1024 + 512 + lane*8);
        }
        #pragma unroll
        for (int m = 0; m < 4; ++m)
            #pragma unroll
            for (int n = 0; n < 4; ++n) {
                acc[m][n] = MFMA16(ah[m], bh[n], acc[m][n]);
                acc[m][n] = MFMA16(ah[m], bl[n], acc[m][n]);
                acc[m][n] = MFMA16(al[m], bh[n], acc[m][n]);
            }
    }

    const int rowW = mb*128 + wr*64;
    const int colW = nb*128 + wc*64;
    if (MODE == 1) {
        #pragma unroll
        for (int m = 0; m < 4; ++m)
            #pragma unroll
            for (int n = 0; n < 4; ++n) {
                const int col = colW + n*16 + (lane & 15);
                const float bv = bias[col];
                #pragma unroll
                for (int r = 0; r < 4; ++r) {
                    const int row = rowW + m*16 + (lane >> 4)*4 + r;
                    outF[(size_t)row * D_MODEL + col] = acc[m][n][r] + bv;
                }
            }
    } else {
        #pragma unroll
        for (int m = 0; m < 4; ++m)
            #pragma unroll
            for (int n = 0; n < 4; ++n) {
                const int col = colW + n*16 + (lane & 15);
                const int which = col / D_MODEL;
                const int c = col % D_MODEL;
                const int h = c >> 6, d = c & 63;
                const float bv = bias[col];
                unsigned short* dstB = (which == 0) ? outQ : (which == 1) ? outK : outV;
                #pragma unroll
                for (int r = 0; r < 4; ++r) {
                    const int row = rowW + m*16 + (lane >> 4)*4 + r;
                    const int b = row >> 10, sq = row & 1023;
                    float val = acc[m][n][r] + bv;
                    if (which == 0) val *= QSCALE;       // fold softmax scale into Q
                    int sub, lp, slot;
                    if (which == 2) {                    // V: B-frag, outer=d, k=seq
                        sub  = (d >> 4)*32 + (sq >> 5);
                        lp   = (d & 15) + (((sq & 31) >> 3) << 4);
                        slot = sq & 7;
                    } else {                             // Q/K: outer=seq, k=d
                        sub  = (sq >> 4)*2 + (d >> 5);
                        lp   = (sq & 15) + (((d & 31) >> 3) << 4);
                        slot = d & 7;
                    }
                    unsigned short hi, lo; split2(val, hi, lo);
                    unsigned short* p = dstB + (size_t)(b*NHEADS + h)*131072
                                      + (size_t)sub*1024 + lp*8 + slot;
                    p[0]   = hi;
                    p[512] = lo;
                }
            }
    }
}

// ---- flash attention on fragments: 4 waves x 32 q-rows, KV tiles of 64 -------
// LDS 40KB (K full 16K + V-hi 8K + P-hi 16K) -> 4 blocks/CU.
// PV uses hi-only P and V (error averaged by softmax normalization).
// Defer-max (THR=8) skips rescale most tiles; softmax in exp2 domain.
__global__ __launch_bounds__(256, 4)
void attn_frag(const unsigned short* __restrict__ Qf,
               const unsigned short* __restrict__ Kf,
               const unsigned short* __restrict__ Vf,
               unsigned short* __restrict__ Cf)
{
    __shared__ unsigned short Ksm[8 * 1024];   // 4 jn x 2 kt full subtiles
    __shared__ unsigned short Vsm[8 * 512];    // 4 dt x 2 kt2 hi-planes
    __shared__ unsigned short Psm[4 * 2048];   // per-wave P: 4 subtiles x 512 bf16

    const int t = threadIdx.x, lane = t & 63, wid = t >> 6;
    // XCD swizzle: all 8 q-blocks of one (b,h) land on the same XCD
    const int bid = blockIdx.x;
    const int qb  = (bid >> 3) & 7;
    const int bh  = (bid & 7) * 12 + (bid >> 6);
    const int mt0 = qb*8 + wid*2;              // wave's first q-subtile (of 64)
    const size_t bhBase = (size_t)bh * 131072;

    const int slot  = lane & 7;
    const int colg  = (lane & 15) >> 3;        // 0/1
    const int qrow0 = (lane >> 4) * 4;         // 0,4,8,12

    // Q fragments live in registers (already scaled by QSCALE)
    bf16x8 qh[2][2], ql[2][2];
    #pragma unroll
    for (int m = 0; m < 2; ++m)
        #pragma unroll
        for (int kt = 0; kt < 2; ++kt) {
            const unsigned short* p = Qf + bhBase + ((size_t)(mt0 + m)*2 + kt)*1024 + lane*8;
            qh[m][kt] = *(const bf16x8*)(p);
            ql[m][kt] = *(const bf16x8*)(p + 512);
        }

    f32x4 out[2][4] = {};
    float m_run[2][4], l_run[2][4];
    #pragma unroll
    for (int m = 0; m < 2; ++m)
        #pragma unroll
        for (int r = 0; r < 4; ++r) { m_run[m][r] = -INFINITY; l_run[m][r] = 0.f; }

    unsigned short* Pw = Psm + wid * 2048;

    for (int jt = 0; jt < 16; ++jt) {
        __syncthreads();                       // prev tile's K/V reads done
        // stage K tile (16KB, full hi+lo): 4 issues/thread
        #pragma unroll
        for (int i = 0; i < 4; ++i) {
            const int id = i*256 + t;
            const unsigned short* gk = Kf + bhBase + (size_t)(jt*8 + (id >> 7))*1024 + (id & 127)*8;
            gload16(gk, (const char*)Ksm + (size_t)(i*256 + wid*64)*16);
        }
        // stage V hi-planes (8KB): wave wid stages chunks 2wid, 2wid+1
        #pragma unroll
        for (int c = 0; c < 2; ++c) {
            const int ch = wid*2 + c;                    // dt = ch>>1, kt2 = ch&1
            const unsigned short* gv = Vf + bhBase
                + (size_t)((ch >> 1)*32 + jt*2 + (ch & 1))*1024 + lane*8;
            gload16(gv, (const char*)Vsm + (size_t)ch*1024);
        }
        __syncthreads();                       // staging complete (vmcnt drained)

        // S = Q K^T (lane owns col j = lane&15 (+16jn), rows q = qrow0+r)
        f32x4 s[2][4] = {};
        #pragma unroll
        for (int jn = 0; jn < 4; ++jn)
            #pragma unroll
            for (int kt = 0; kt < 2; ++kt) {
                const bf16x8 kh = *(const bf16x8*)(Ksm + (jn*2 + kt)*1024 + lane*8);
                const bf16x8 kl = *(const bf16x8*)(Ksm + (jn*2 + kt)*1024 + 512 + lane*8);
                #pragma unroll
                for (int m = 0; m < 2; ++m) {
                    s[m][jn] = MFMA16(qh[m][kt], kh, s[m][jn]);
                    s[m][jn] = MFMA16(qh[m][kt], kl, s[m][jn]);
                    s[m][jn] = MFMA16(ql[m][kt], kh, s[m][jn]);
                }
            }

        // in-lane partial max -> wave-uniform skip predicate (defer-max, THR=8)
        float mx[2][4];
        int ok = 1;
        #pragma unroll
        for (int m = 0; m < 2; ++m)
            #pragma unroll
            for (int r = 0; r < 4; ++r) {
                const float v = fmaxf(fmaxf(s[m][0][r], s[m][1][r]),
                                      fmaxf(s[m][2][r], s[m][3][r]));
                mx[m][r] = v;
                ok &= (v <= m_run[m][r] + 8.0f);
            }
        if (!__all(ok)) {
            float alf[2][4];
            #pragma unroll
            for (int m = 0; m < 2; ++m)
                #pragma unroll
                for (int r = 0; r < 4; ++r) {
                    float v = mx[m][r];
                    #pragma unroll
                    for (int msk = 1; msk < 16; msk <<= 1)
                        v = fmaxf(v, __shfl_xor(v, msk));
                    const float mn = fmaxf(m_run[m][r], v);
                    const float a  = exp2_fast(m_run[m][r] - mn);
                    m_run[m][r] = mn;
                    l_run[m][r] *= a;
                    alf[m][r] = a;
                }
            #pragma unroll
            for (int m = 0; m < 2; ++m)
                #pragma unroll
                for (int dt = 0; dt < 4; ++dt)
                    #pragma unroll
                    for (int r = 0; r < 4; ++r)
                        out[m][dt][r] *= alf[m][r];
        }

        // P = exp2(s - m), rowsum in f32, store bf16-hi into swizzled A-frag LDS
        #pragma unroll
        for (int m = 0; m < 2; ++m)
            #pragma unroll
            for (int r = 0; r < 4; ++r) {
                const float mb_ = m_run[m][r];
                float e[4];
                #pragma unroll
                for (int jn = 0; jn < 4; ++jn) e[jn] = exp2_fast(s[m][jn][r] - mb_);
                float rs = (e[0] + e[1]) + (e[2] + e[3]);
                #pragma unroll
                for (int msk = 1; msk < 16; msk <<= 1)
                    rs += __shfl_xor(rs, msk);
                l_run[m][r] += rs;
                // tlane = (qrow0+r) + 16*colg (+32*(jn&1) handled as +256 idx)
                const int tl   = qrow0 + r + (colg << 4);
                const int idxb = ((tl << 3) | slot) ^ (tl & 0x18);
                #pragma unroll
                for (int jn = 0; jn < 4; ++jn)
                    Pw[(m*2 + (jn >> 1))*512 + idxb + ((jn & 1) << 8)] = f2bf(e[jn]);
            }

        // PV: read P back as bf16x8 A-frags (wave-local), V-hi from LDS
        const int rdswz = (lane*8) ^ (lane & 0x18);
        #pragma unroll
        for (int kt2 = 0; kt2 < 2; ++kt2) {
            bf16x8 pa[2];
            #pragma unroll
            for (int m = 0; m < 2; ++m)
                pa[m] = *(const bf16x8*)(Pw + (m*2 + kt2)*512 + rdswz);
            #pragma unroll
            for (int dt = 0; dt < 4; ++dt) {
                const bf16x8 vh = *(const bf16x8*)(Vsm + (dt*2 + kt2)*512 + lane*8);
                #pragma unroll
                for (int m = 0; m < 2; ++m)
                    out[m][dt] = MFMA16(pa[m], vh, out[m][dt]);
            }
        }
    }

    // epilogue: ctx / l  ->  proj-GEMM A-fragments
    const int b = bh / NHEADS, h = bh % NHEADS;
    #pragma unroll
    for (int m = 0; m < 2; ++m)
        #pragma unroll
        for (int r = 0; r < 4; ++r) {
            const float inv = 1.0f / l_run[m][r];
            const int sq = (mt0 + m)*16 + qrow0 + r;
            const int mrow = b*SEQ + sq;
            #pragma unroll
            for (int dt = 0; dt < 4; ++dt) {
                const int c = h*64 + dt*16 + (lane & 15);
                const float val = out[m][dt][r] * inv;
                unsigned short hi, lo; split2(val, hi, lo);
                unsigned short* p = Cf + ((size_t)(mrow >> 4)*KT_D + (c >> 5))*1024
                                  + ((mrow & 15) + (((c & 31) >> 3) << 4))*8 + (c & 7);
                p[0]   = hi;
                p[512] = lo;
            }
        }
}

// ---------------------------------------------------------------------------
extern "C" void kernel_launch(void* const* d_in, const int* in_sizes, int n_in,
                              void* d_out, int out_size, void* d_ws, size_t ws_size,
                              hipStream_t stream)
{
    const float* x      = (const float*)d_in[0];
    const float* w_qkv  = (const float*)d_in[1];
    const float* b_qkv  = (const float*)d_in[2];
    const float* w_proj = (const float*)d_in[3];
    const float* b_proj = (const float*)d_in[4];
    float* out = (float*)d_out;

    unsigned short* ws = (unsigned short*)d_ws;
    unsigned short* Xf = ws;                    // 512*24*1024        = 12,582,912
    unsigned short* Wq = Xf + 12582912;         // 144*24*1024        =  3,538,944
    unsigned short* Wp = Wq + 3538944;          //  48*24*1024        =  1,179,648
    unsigned short* Qf = Wp + 1179648;          //  96*131072         = 12,582,912
    unsigned short* Kf = Qf + 12582912;
    unsigned short* Vf = Kf + 12582912;
    unsigned short* Cf = Vf + 12582912;         // 512*24*1024
    // total = 67,633,152 ushorts = 135.3 MB of d_ws

    convert_a<<<dim3(3072), 256, 0, stream>>>(x, Xf, KT_D, D_MODEL, 1.0f, 786432);
    convert_b<<<dim3(864),  256, 0, stream>>>(w_qkv, Wq, KT_D, QKV_COLS, 221184);
    convert_b<<<dim3(288),  256, 0, stream>>>(w_proj, Wp, KT_D, D_MODEL, 73728);

    gemm_frag<0><<<dim3(1152), 256, 0, stream>>>(Xf, Wq, b_qkv, nullptr, Qf, Kf, Vf);
    attn_frag<<<dim3(768), 256, 0, stream>>>(Qf, Kf, Vf, Cf);
    gemm_frag<1><<<dim3(384), 256, 0, stream>>>(Cf, Wp, b_proj, out,
                                                nullptr, nullptr, nullptr);
}